// Round 2
// baseline (478.167 us; speedup 1.0000x reference)
//
#include <hip/hip_runtime.h>

typedef __attribute__((ext_vector_type(8))) short short8;
typedef __attribute__((ext_vector_type(4))) short short4v;
typedef __attribute__((ext_vector_type(4))) float float4v;
typedef __attribute__((ext_vector_type(8))) __bf16 bf16x8;

// LDS layout (bytes):
//   region A  [0, 57344)        : XT bf16[49][512] (swizzled) during GEMMs; VT[8][64][56] after V
//   PQ        [57344, 107520)   : P_q bf16 flat s*128+dd*2 (swizzled)   (50176 B)
//   PK        [107520, 157696)  : P_k same                              (50176 B)
//   attn ovl  [57344, 122880)   : per-head attn bf16 [64][64] swizzled (overlays PQ/PK after QK^T)
//   BIAS      [157696, 163104)  : bias_table f32 [169][8]
#define LDS_PQ 57344
#define LDS_PK 107520
#define LDS_BIAS 157696
#define LDS_TOTAL 163104

__device__ __forceinline__ unsigned short f2bf(float f) {
  unsigned u = __float_as_uint(f);
  u += 0x7FFFu + ((u >> 16) & 1u);   // RNE
  return (unsigned short)(u >> 16);
}

// ---- kernel 1: convert q_w/k_w/v_w fp32 -> bf16 into workspace ----
__global__ void wconv_kernel(const float* __restrict__ qw, const float* __restrict__ kw,
                             const float* __restrict__ vw, short* __restrict__ out) {
  int g = blockIdx.x >> 8;  // 0:q 1:k 2:v
  const float* src = (g == 0) ? qw : (g == 1) ? kw : vw;
  int off = ((blockIdx.x & 255) * 256 + threadIdx.x) * 4;
  float4v v = *(const float4v*)(src + off);
  short4v o;
  o.x = (short)f2bf(v.x); o.y = (short)f2bf(v.y);
  o.z = (short)f2bf(v.z); o.w = (short)f2bf(v.w);
  *(short4v*)(out + g * 262144 + off) = o;
}

// ---- kernel 2: fused windowed attention, one 1024-thread workgroup per (b, window) ----
// 16 waves: GEMM phase each wave owns 32 N-columns; attention phase wave pair
// (h, h+8) shares head h=wave&7, duplicating QK^T+softmax and splitting PV cols.
__global__ __launch_bounds__(1024, 4) void wattn_kernel(
    const float* __restrict__ x, const short* __restrict__ wcvt,
    const float* __restrict__ qb, const float* __restrict__ kb, const float* __restrict__ vb,
    const float* __restrict__ btab, float* __restrict__ out) {
  __shared__ __align__(16) char sm[LDS_TOTAL];
  const int tid  = threadIdx.x;
  const int lane = tid & 63;
  const int wave = tid >> 6;       // 0..15
  const int bwi  = blockIdx.x;     // b*64 + wi
  const int bb   = bwi >> 6, wi = bwi & 63;
  const int l15  = lane & 15;
  const int l4   = lane >> 4;
  const int ig   = l4 * 4;

  // stage bias table (f32, 169*8)
  for (int i = tid; i < 169 * 8; i += 1024)
    *(float*)(sm + LDS_BIAS + i * 4) = btab[i];

  // stage x tile -> XT bf16 [49][512], row-XOR swizzle
  {
    const float* xb = x + (size_t)bb * (3136 * 512);
    const int whi = (wi >> 3) * 7, wlo = (wi & 7) * 7;
    for (int idx = tid; idx < 49 * 128; idx += 1024) {
      int t = idx >> 7, c4 = idx & 127;
      int yt = (t * 37) >> 8, xt = t - yt * 7;
      int l = (whi + yt) * 56 + wlo + xt;
      float4v v = *(const float4v*)(xb + l * 512 + c4 * 4);
      short4v o;
      o.x = (short)f2bf(v.x); o.y = (short)f2bf(v.y);
      o.z = (short)f2bf(v.z); o.w = (short)f2bf(v.w);
      int byte = t * 1024 + c4 * 8;
      *(short4v*)(sm + (byte ^ ((t & 7) << 4))) = o;
    }
  }
  __syncthreads();

  const int wcol = wave * 32;

  // ---- three projection GEMMs: P = XT @ W^T + b ----
  for (int g = 0; g < 3; ++g) {
    const short* wt = wcvt + g * 262144;
    const float* bias = (g == 0) ? qb : (g == 1) ? kb : vb;
    float4v acc[4][2];
#pragma unroll
    for (int m = 0; m < 4; ++m)
#pragma unroll
      for (int n = 0; n < 2; ++n) acc[m][n] = (float4v)0.f;

    for (int kk = 0; kk < 16; ++kk) {
      const int k0 = kk * 32 + l4 * 8;
      bf16x8 a[4], b[2];
#pragma unroll
      for (int m = 0; m < 4; ++m) {
        int row = m * 16 + l15;
        if (row < 49) {
          int byte = row * 1024 + k0 * 2;
          a[m] = __builtin_bit_cast(bf16x8, *(const short8*)(sm + (byte ^ ((row & 7) << 4))));
        } else {
          a[m] = __builtin_bit_cast(bf16x8, (short8)0);
        }
      }
#pragma unroll
      for (int n = 0; n < 2; ++n) {
        int o = wcol + n * 16 + l15;
        b[n] = __builtin_bit_cast(bf16x8, *(const short8*)(wt + o * 512 + k0));
      }
#pragma unroll
      for (int m = 0; m < 4; ++m)
#pragma unroll
        for (int n = 0; n < 2; ++n)
          acc[m][n] = __builtin_amdgcn_mfma_f32_16x16x32_bf16(a[m], b[n], acc[m][n], 0, 0, 0);
    }

    if (g < 2) {
      const int base = (g == 0) ? LDS_PQ : LDS_PK;
#pragma unroll
      for (int n = 0; n < 2; ++n) {
        int o = wcol + n * 16 + l15;
        float bv = bias[o];
#pragma unroll
        for (int m = 0; m < 4; ++m)
#pragma unroll
          for (int r = 0; r < 4; ++r) {
            int t = m * 16 + ig + r;
            if (t < 49) {
              int s = t * 8 + (o >> 6);
              int flat = s * 128 + (o & 63) * 2;
              *(unsigned short*)(sm + base + (flat ^ ((s & 7) << 4))) = f2bf(acc[m][n][r] + bv);
            }
          }
      }
    } else {
      __syncthreads();  // all waves done reading XT; region A becomes VT
#pragma unroll
      for (int n = 0; n < 2; ++n) {
        int o = wcol + n * 16 + l15;
        float bv = bias[o];
        int dd = o & 63;
#pragma unroll
        for (int m = 0; m < 4; ++m)
#pragma unroll
          for (int r = 0; r < 4; ++r) {
            int t = m * 16 + ig + r;
            if (t < 49) {
              int s = t * 8 + (o >> 6);
              int h2 = (s * 1339) >> 16;       // s / 49
              int tp = s - h2 * 49;
              *(unsigned short*)(sm + h2 * 7168 + dd * 112 + tp * 2) = f2bf(acc[m][n][r] + bv);
            }
          }
      }
      // zero VT pads t' = 49..55 (read by PV B-fragments)
      if (tid < 512) {
        int h2 = tid >> 6, dd = tid & 63;
        char* p = sm + h2 * 7168 + dd * 112;
#pragma unroll
        for (int q = 49; q < 56; ++q) *(unsigned short*)(p + q * 2) = 0;
      }
      __syncthreads();
    }
  }

  // ---- attention: wave pair (h, h+8) -> head h; 'half' splits PV/output cols ----
  const int h    = wave & 7;
  const int half = wave >> 3;
  const float* bias_f = (const float*)(sm + LDS_BIAS);

  float4v sc[4][4];
#pragma unroll
  for (int m = 0; m < 4; ++m)
#pragma unroll
    for (int n = 0; n < 4; ++n) sc[m][n] = (float4v)0.f;

  for (int ks = 0; ks < 2; ++ks) {
    const int dd = ks * 32 + l4 * 8;
    bf16x8 a[4], b[4];
#pragma unroll
    for (int m = 0; m < 4; ++m) {
      int tp = m * 16 + l15;
      if (tp < 49) {
        int s = h * 49 + tp;
        int flat = s * 128 + dd * 2;
        a[m] = __builtin_bit_cast(bf16x8, *(const short8*)(sm + LDS_PQ + (flat ^ ((s & 7) << 4))));
      } else {
        a[m] = __builtin_bit_cast(bf16x8, (short8)0);
      }
    }
#pragma unroll
    for (int n = 0; n < 4; ++n) {
      int tp = n * 16 + l15;
      if (tp < 49) {
        int s = h * 49 + tp;
        int flat = s * 128 + dd * 2;
        b[n] = __builtin_bit_cast(bf16x8, *(const short8*)(sm + LDS_PK + (flat ^ ((s & 7) << 4))));
      } else {
        b[n] = __builtin_bit_cast(bf16x8, (short8)0);
      }
    }
#pragma unroll
    for (int m = 0; m < 4; ++m)
#pragma unroll
      for (int n = 0; n < 4; ++n)
        sc[m][n] = __builtin_amdgcn_mfma_f32_16x16x32_bf16(a[m], b[n], sc[m][n], 0, 0, 0);
  }

  // softmax (rows i across 16 lanes of same l4 group + 4 n-tiles in-register)
#pragma unroll
  for (int m = 0; m < 4; ++m)
#pragma unroll
    for (int r = 0; r < 4; ++r) {
      int i = m * 16 + ig + r;
      int yi = (i * 37) >> 8, xi = i - yi * 7;
      float rowv[4];
      float mx = -1e30f;
#pragma unroll
      for (int n = 0; n < 4; ++n) {
        int j = n * 16 + l15;
        float v = -1e30f;
        if (i < 49 && j < 49) {
          int yj = (j * 37) >> 8, xj = j - yj * 7;
          int idx = (yi - yj + 6) * 13 + (xi - xj + 6);
          v = sc[m][n][r] * 0.125f + bias_f[idx * 8 + h];
        }
        rowv[n] = v;
        mx = fmaxf(mx, v);
      }
      mx = fmaxf(mx, __shfl_xor(mx, 1));
      mx = fmaxf(mx, __shfl_xor(mx, 2));
      mx = fmaxf(mx, __shfl_xor(mx, 4));
      mx = fmaxf(mx, __shfl_xor(mx, 8));
      float ssum = 0.f;
#pragma unroll
      for (int n = 0; n < 4; ++n) {
        float e = (rowv[n] > -1e29f) ? __expf(rowv[n] - mx) : 0.f;
        rowv[n] = e;
        ssum += e;
      }
      ssum += __shfl_xor(ssum, 1);
      ssum += __shfl_xor(ssum, 2);
      ssum += __shfl_xor(ssum, 4);
      ssum += __shfl_xor(ssum, 8);
      float inv = 1.f / ssum;
#pragma unroll
      for (int n = 0; n < 4; ++n) sc[m][n][r] = rowv[n] * inv;
    }

  __syncthreads();  // Pq/Pk dead for ALL waves -> overlay attn (per head, [64][64] bf16 swizzled)
  const int ovb = LDS_PQ + h * 8192;
#pragma unroll
  for (int m = 0; m < 4; ++m)
#pragma unroll
    for (int r = 0; r < 4; ++r) {
      int i = m * 16 + ig + r;
      if (i < 49) {
        int rowbase = i * 128;
        int swz = (i & 7) << 4;
#pragma unroll
        for (int n = 0; n < 2; ++n) {
          int gn = half * 2 + n;               // each pair-half writes 2 of the 4 n-tiles
          int j = gn * 16 + l15;
          *(unsigned short*)(sm + ovb + ((rowbase + j * 2) ^ swz)) = f2bf(sc[m][gn][r]);
        }
      }
    }
  __syncthreads();

  // PV: out = attn @ V  (B-fragments from VT[h][dd][t']); each pair-half does 32 dd cols
  float4v oacc[4][2];
#pragma unroll
  for (int m = 0; m < 4; ++m)
#pragma unroll
    for (int n = 0; n < 2; ++n) oacc[m][n] = (float4v)0.f;

  for (int ks = 0; ks < 2; ++ks) {
    const int tp0 = ks * 32 + l4 * 8;
    bf16x8 a[4], b[2];
#pragma unroll
    for (int m = 0; m < 4; ++m) {
      int i = m * 16 + l15;
      int flat = i * 128 + tp0 * 2;
      a[m] = __builtin_bit_cast(bf16x8, *(const short8*)(sm + ovb + (flat ^ ((i & 7) << 4))));
    }
    const int tt = (tp0 >= 56) ? 0 : tp0;  // clamp: attn cols >=49 are zero anyway
#pragma unroll
    for (int n = 0; n < 2; ++n) {
      int dd = half * 32 + n * 16 + l15;
      b[n] = __builtin_bit_cast(bf16x8, *(const short8*)(sm + h * 7168 + dd * 112 + tt * 2));
    }
#pragma unroll
    for (int m = 0; m < 4; ++m)
#pragma unroll
      for (int n = 0; n < 2; ++n)
        oacc[m][n] = __builtin_amdgcn_mfma_f32_16x16x32_bf16(a[m], b[n], oacc[m][n], 0, 0, 0);
  }

  // output: flat [b][wi][h][t'][dd]
  float* op = out + (size_t)bwi * 25088 + h * 3136;
#pragma unroll
  for (int m = 0; m < 4; ++m)
#pragma unroll
    for (int r = 0; r < 4; ++r) {
      int tp = m * 16 + ig + r;
      if (tp < 49) {
#pragma unroll
        for (int n = 0; n < 2; ++n)
          op[tp * 64 + half * 32 + n * 16 + l15] = oacc[m][n][r];
      }
    }
}

extern "C" void kernel_launch(void* const* d_in, const int* in_sizes, int n_in,
                              void* d_out, int out_size, void* d_ws, size_t ws_size,
                              hipStream_t stream) {
  const float* x    = (const float*)d_in[0];
  const float* q_w  = (const float*)d_in[1];
  const float* q_b  = (const float*)d_in[2];
  const float* k_w  = (const float*)d_in[3];
  const float* k_b  = (const float*)d_in[4];
  const float* v_w  = (const float*)d_in[5];
  const float* v_b  = (const float*)d_in[6];
  const float* btab = (const float*)d_in[7];
  short* wcvt = (short*)d_ws;  // 3 * 512 * 512 bf16 = 1.5 MB

  hipLaunchKernelGGL(wconv_kernel, dim3(768), dim3(256), 0, stream, q_w, k_w, v_w, wcvt);
  hipLaunchKernelGGL(wattn_kernel, dim3(1024), dim3(1024), 0, stream,
                     x, wcvt, q_b, k_b, v_b, btab, (float*)d_out);
}

// Round 3
// 340.907 us; speedup vs baseline: 1.4026x; 1.4026x over previous
//
#include <hip/hip_runtime.h>

typedef __attribute__((ext_vector_type(8))) short short8;
typedef __attribute__((ext_vector_type(4))) short short4v;
typedef __attribute__((ext_vector_type(4))) float float4v;
typedef __attribute__((ext_vector_type(8))) __bf16 bf16x8;

// LDS layout (bytes):
//   region A  [0, 57344)        : XT bf16[49][512] (swizzled) during GEMMs; VT[8][64][56] after V
//   PQ        [57344, 107520)   : P_q bf16 flat s*128+dd*2 (swizzled)   (50176 B)
//   PK        [107520, 157696)  : P_k same
//   attn ovl  [57344, 122880)   : per-head attn bf16 [64][64] swizzled (overlays PQ/PK after QK^T)
//   BIAS      [157696, 163104)  : bias_table f32 [169][8]
#define LDS_PQ 57344
#define LDS_PK 107520
#define LDS_BIAS 157696
#define LDS_TOTAL 163104

__device__ __forceinline__ unsigned short f2bf(float f) {
  unsigned u = __float_as_uint(f);
  u += 0x7FFFu + ((u >> 16) & 1u);   // RNE
  return (unsigned short)(u >> 16);
}

// ---- kernel 1: convert q_w/k_w/v_w fp32 -> bf16 into workspace ----
__global__ void wconv_kernel(const float* __restrict__ qw, const float* __restrict__ kw,
                             const float* __restrict__ vw, short* __restrict__ out) {
  int g = blockIdx.x >> 8;  // 0:q 1:k 2:v
  const float* src = (g == 0) ? qw : (g == 1) ? kw : vw;
  int off = ((blockIdx.x & 255) * 256 + threadIdx.x) * 4;
  float4v v = *(const float4v*)(src + off);
  short4v o;
  o.x = (short)f2bf(v.x); o.y = (short)f2bf(v.y);
  o.z = (short)f2bf(v.z); o.w = (short)f2bf(v.w);
  *(short4v*)(out + g * 262144 + off) = o;
}

// ---- kernel 2: fused windowed attention, one 1024-thread workgroup per (b, window) ----
// 16 waves. GEMM phase: each wave owns 32 N-columns (acc[4][2], ~56 live regs).
// Attention phase: wave pair (h, h+8) shares head h = wave&7 and SPLITS BY ROWS:
// half=wave>>3 owns m-tiles {half*2, half*2+1} (rows half*32 .. half*32+31).
// Softmax is per-row so the halves are independent -> no duplicated work and
// per-wave register arrays halve (sc[2][4], oacc[2][4]) -> fits 4 waves/SIMD
// without scratch spills (round-2 failure mode: 1.2 GB/dispatch spill traffic).
__global__ __launch_bounds__(1024, 4) void wattn_kernel(
    const float* __restrict__ x, const short* __restrict__ wcvt,
    const float* __restrict__ qb, const float* __restrict__ kb, const float* __restrict__ vb,
    const float* __restrict__ btab, float* __restrict__ out) {
  __shared__ __align__(16) char sm[LDS_TOTAL];
  const int tid  = threadIdx.x;
  const int lane = tid & 63;
  const int wave = tid >> 6;       // 0..15
  const int bwi  = blockIdx.x;     // b*64 + wi
  const int bb   = bwi >> 6, wi = bwi & 63;
  const int l15  = lane & 15;
  const int l4   = lane >> 4;
  const int ig   = l4 * 4;

  // stage bias table (f32, 169*8)
  for (int i = tid; i < 169 * 8; i += 1024)
    *(float*)(sm + LDS_BIAS + i * 4) = btab[i];

  // stage x tile -> XT bf16 [49][512], row-XOR swizzle
  {
    const float* xb = x + (size_t)bb * (3136 * 512);
    const int whi = (wi >> 3) * 7, wlo = (wi & 7) * 7;
    for (int idx = tid; idx < 49 * 128; idx += 1024) {
      int t = idx >> 7, c4 = idx & 127;
      int yt = (t * 37) >> 8, xt = t - yt * 7;
      int l = (whi + yt) * 56 + wlo + xt;
      float4v v = *(const float4v*)(xb + l * 512 + c4 * 4);
      short4v o;
      o.x = (short)f2bf(v.x); o.y = (short)f2bf(v.y);
      o.z = (short)f2bf(v.z); o.w = (short)f2bf(v.w);
      int byte = t * 1024 + c4 * 8;
      *(short4v*)(sm + (byte ^ ((t & 7) << 4))) = o;
    }
  }
  __syncthreads();

  const int wcol = wave * 32;

  // ---- three projection GEMMs: P = XT @ W^T + b ----
  for (int g = 0; g < 3; ++g) {
    const short* wt = wcvt + g * 262144;
    const float* bias = (g == 0) ? qb : (g == 1) ? kb : vb;
    float4v acc[4][2];
#pragma unroll
    for (int m = 0; m < 4; ++m)
#pragma unroll
      for (int n = 0; n < 2; ++n) acc[m][n] = (float4v)0.f;

    for (int kk = 0; kk < 16; ++kk) {
      const int k0 = kk * 32 + l4 * 8;
      bf16x8 a[4], b[2];
#pragma unroll
      for (int m = 0; m < 4; ++m) {
        int row = m * 16 + l15;
        if (row < 49) {
          int byte = row * 1024 + k0 * 2;
          a[m] = __builtin_bit_cast(bf16x8, *(const short8*)(sm + (byte ^ ((row & 7) << 4))));
        } else {
          a[m] = __builtin_bit_cast(bf16x8, (short8)0);
        }
      }
#pragma unroll
      for (int n = 0; n < 2; ++n) {
        int o = wcol + n * 16 + l15;
        b[n] = __builtin_bit_cast(bf16x8, *(const short8*)(wt + o * 512 + k0));
      }
#pragma unroll
      for (int m = 0; m < 4; ++m)
#pragma unroll
        for (int n = 0; n < 2; ++n)
          acc[m][n] = __builtin_amdgcn_mfma_f32_16x16x32_bf16(a[m], b[n], acc[m][n], 0, 0, 0);
    }

    if (g < 2) {
      const int base = (g == 0) ? LDS_PQ : LDS_PK;
#pragma unroll
      for (int n = 0; n < 2; ++n) {
        int o = wcol + n * 16 + l15;
        float bv = bias[o];
#pragma unroll
        for (int m = 0; m < 4; ++m)
#pragma unroll
          for (int r = 0; r < 4; ++r) {
            int t = m * 16 + ig + r;
            if (t < 49) {
              int s = t * 8 + (o >> 6);
              int flat = s * 128 + (o & 63) * 2;
              *(unsigned short*)(sm + base + (flat ^ ((s & 7) << 4))) = f2bf(acc[m][n][r] + bv);
            }
          }
      }
    } else {
      __syncthreads();  // all waves done reading XT; region A becomes VT
#pragma unroll
      for (int n = 0; n < 2; ++n) {
        int o = wcol + n * 16 + l15;
        float bv = bias[o];
        int dd = o & 63;
#pragma unroll
        for (int m = 0; m < 4; ++m)
#pragma unroll
          for (int r = 0; r < 4; ++r) {
            int t = m * 16 + ig + r;
            if (t < 49) {
              int s = t * 8 + (o >> 6);
              int h2 = (s * 1339) >> 16;       // s / 49
              int tp = s - h2 * 49;
              *(unsigned short*)(sm + h2 * 7168 + dd * 112 + tp * 2) = f2bf(acc[m][n][r] + bv);
            }
          }
      }
      // zero VT pads t' = 49..55 (read by PV B-fragments)
      if (tid < 512) {
        int h2 = tid >> 6, dd = tid & 63;
        char* p = sm + h2 * 7168 + dd * 112;
#pragma unroll
        for (int q = 49; q < 56; ++q) *(unsigned short*)(p + q * 2) = 0;
      }
      __syncthreads();
    }
  }

  // ---- attention: wave pair (h, h+8) -> head h; 'half' owns row m-tiles {half*2, half*2+1} ----
  const int h    = wave & 7;
  const int half = wave >> 3;
  const float* bias_f = (const float*)(sm + LDS_BIAS);

  float4v sc[2][4];
#pragma unroll
  for (int mm = 0; mm < 2; ++mm)
#pragma unroll
    for (int n = 0; n < 4; ++n) sc[mm][n] = (float4v)0.f;

  for (int ks = 0; ks < 2; ++ks) {
    const int dd = ks * 32 + l4 * 8;
    bf16x8 a[2], b[4];
#pragma unroll
    for (int mm = 0; mm < 2; ++mm) {
      int tp = (half * 2 + mm) * 16 + l15;
      if (tp < 49) {
        int s = h * 49 + tp;
        int flat = s * 128 + dd * 2;
        a[mm] = __builtin_bit_cast(bf16x8, *(const short8*)(sm + LDS_PQ + (flat ^ ((s & 7) << 4))));
      } else {
        a[mm] = __builtin_bit_cast(bf16x8, (short8)0);
      }
    }
#pragma unroll
    for (int n = 0; n < 4; ++n) {
      int tp = n * 16 + l15;
      if (tp < 49) {
        int s = h * 49 + tp;
        int flat = s * 128 + dd * 2;
        b[n] = __builtin_bit_cast(bf16x8, *(const short8*)(sm + LDS_PK + (flat ^ ((s & 7) << 4))));
      } else {
        b[n] = __builtin_bit_cast(bf16x8, (short8)0);
      }
    }
#pragma unroll
    for (int mm = 0; mm < 2; ++mm)
#pragma unroll
      for (int n = 0; n < 4; ++n)
        sc[mm][n] = __builtin_amdgcn_mfma_f32_16x16x32_bf16(a[mm], b[n], sc[mm][n], 0, 0, 0);
  }

  // softmax on this wave's rows (i across 16 lanes of same l4 group + 4 n-tiles in-register)
#pragma unroll
  for (int mm = 0; mm < 2; ++mm)
#pragma unroll
    for (int r = 0; r < 4; ++r) {
      int i = (half * 2 + mm) * 16 + ig + r;
      int yi = (i * 37) >> 8, xi = i - yi * 7;
      float rowv[4];
      float mx = -1e30f;
#pragma unroll
      for (int n = 0; n < 4; ++n) {
        int j = n * 16 + l15;
        float v = -1e30f;
        if (i < 49 && j < 49) {
          int yj = (j * 37) >> 8, xj = j - yj * 7;
          int idx = (yi - yj + 6) * 13 + (xi - xj + 6);
          v = sc[mm][n][r] * 0.125f + bias_f[idx * 8 + h];
        }
        rowv[n] = v;
        mx = fmaxf(mx, v);
      }
      mx = fmaxf(mx, __shfl_xor(mx, 1));
      mx = fmaxf(mx, __shfl_xor(mx, 2));
      mx = fmaxf(mx, __shfl_xor(mx, 4));
      mx = fmaxf(mx, __shfl_xor(mx, 8));
      float ssum = 0.f;
#pragma unroll
      for (int n = 0; n < 4; ++n) {
        float e = (rowv[n] > -1e29f) ? __expf(rowv[n] - mx) : 0.f;
        rowv[n] = e;
        ssum += e;
      }
      ssum += __shfl_xor(ssum, 1);
      ssum += __shfl_xor(ssum, 2);
      ssum += __shfl_xor(ssum, 4);
      ssum += __shfl_xor(ssum, 8);
      float inv = 1.f / ssum;
#pragma unroll
      for (int n = 0; n < 4; ++n) sc[mm][n][r] = rowv[n] * inv;
    }

  __syncthreads();  // Pq/Pk dead for ALL waves -> overlay attn (per head, [64][64] bf16 swizzled)
  const int ovb = LDS_PQ + h * 8192;
#pragma unroll
  for (int mm = 0; mm < 2; ++mm)
#pragma unroll
    for (int r = 0; r < 4; ++r) {
      int i = (half * 2 + mm) * 16 + ig + r;
      if (i < 49) {
        int rowbase = i * 128;
        int swz = (i & 7) << 4;
#pragma unroll
        for (int n = 0; n < 4; ++n) {
          int j = n * 16 + l15;
          *(unsigned short*)(sm + ovb + ((rowbase + j * 2) ^ swz)) = f2bf(sc[mm][n][r]);
        }
      }
    }
  __syncthreads();

  // PV: out = attn @ V  (A rows = this wave's half; B from VT[h][dd][t'], full 64 cols)
  float4v oacc[2][4];
#pragma unroll
  for (int mm = 0; mm < 2; ++mm)
#pragma unroll
    for (int n = 0; n < 4; ++n) oacc[mm][n] = (float4v)0.f;

  for (int ks = 0; ks < 2; ++ks) {
    const int tp0 = ks * 32 + l4 * 8;
    bf16x8 a[2], b[4];
#pragma unroll
    for (int mm = 0; mm < 2; ++mm) {
      int i = (half * 2 + mm) * 16 + l15;
      int flat = i * 128 + tp0 * 2;
      a[mm] = __builtin_bit_cast(bf16x8, *(const short8*)(sm + ovb + (flat ^ ((i & 7) << 4))));
    }
    const int tt = (tp0 >= 56) ? 0 : tp0;  // clamp: attn cols >=49 are zero anyway
#pragma unroll
    for (int n = 0; n < 4; ++n) {
      int dd = n * 16 + l15;
      b[n] = __builtin_bit_cast(bf16x8, *(const short8*)(sm + h * 7168 + dd * 112 + tt * 2));
    }
#pragma unroll
    for (int mm = 0; mm < 2; ++mm)
#pragma unroll
      for (int n = 0; n < 4; ++n)
        oacc[mm][n] = __builtin_amdgcn_mfma_f32_16x16x32_bf16(a[mm], b[n], oacc[mm][n], 0, 0, 0);
  }

  // output: flat [b][wi][h][t'][dd]; full 256-B rows per wave
  float* op = out + (size_t)bwi * 25088 + h * 3136;
#pragma unroll
  for (int mm = 0; mm < 2; ++mm)
#pragma unroll
    for (int r = 0; r < 4; ++r) {
      int tp = (half * 2 + mm) * 16 + ig + r;
      if (tp < 49) {
#pragma unroll
        for (int n = 0; n < 4; ++n)
          op[tp * 64 + n * 16 + l15] = oacc[mm][n][r];
      }
    }
}

extern "C" void kernel_launch(void* const* d_in, const int* in_sizes, int n_in,
                              void* d_out, int out_size, void* d_ws, size_t ws_size,
                              hipStream_t stream) {
  const float* x    = (const float*)d_in[0];
  const float* q_w  = (const float*)d_in[1];
  const float* q_b  = (const float*)d_in[2];
  const float* k_w  = (const float*)d_in[3];
  const float* k_b  = (const float*)d_in[4];
  const float* v_w  = (const float*)d_in[5];
  const float* v_b  = (const float*)d_in[6];
  const float* btab = (const float*)d_in[7];
  short* wcvt = (short*)d_ws;  // 3 * 512 * 512 bf16 = 1.5 MB

  hipLaunchKernelGGL(wconv_kernel, dim3(768), dim3(256), 0, stream, q_w, k_w, v_w, wcvt);
  hipLaunchKernelGGL(wattn_kernel, dim3(1024), dim3(1024), 0, stream,
                     x, wcvt, q_b, k_b, v_b, btab, (float*)d_out);
}

// Round 4
// 254.912 us; speedup vs baseline: 1.8758x; 1.3374x over previous
//
#include <hip/hip_runtime.h>

typedef __attribute__((ext_vector_type(8))) short short8;
typedef __attribute__((ext_vector_type(4))) short short4v;
typedef __attribute__((ext_vector_type(4))) float float4v;
typedef __attribute__((ext_vector_type(8))) __bf16 bf16x8;

// LDS layout (bytes):
//   region A  [0, 57344)        : XT bf16[49][512] (swizzled) during GEMMs; VT[8][64][56] after V
//   PQ        [57344, 107520)   : P_q bf16 flat s*128+dd*2 (swizzled)   (50176 B)
//   PK        [107520, 157696)  : P_k same
//   attn ovl  [57344, 122880)   : per-head attn bf16 [64][64] swizzled (overlays PQ/PK after QK^T)
//   BIAS      [157696, 163104)  : bias_table f32 [169][8]
#define LDS_PQ 57344
#define LDS_PK 107520
#define LDS_BIAS 157696
#define LDS_TOTAL 163104

__device__ __forceinline__ unsigned short f2bf(float f) {
  unsigned u = __float_as_uint(f);
  u += 0x7FFFu + ((u >> 16) & 1u);   // RNE
  return (unsigned short)(u >> 16);
}

// ---- kernel 1: convert q_w/k_w/v_w fp32 -> bf16 into workspace ----
__global__ void wconv_kernel(const float* __restrict__ qw, const float* __restrict__ kw,
                             const float* __restrict__ vw, short* __restrict__ out) {
  int g = blockIdx.x >> 8;  // 0:q 1:k 2:v
  const float* src = (g == 0) ? qw : (g == 1) ? kw : vw;
  int off = ((blockIdx.x & 255) * 256 + threadIdx.x) * 4;
  float4v v = *(const float4v*)(src + off);
  short4v o;
  o.x = (short)f2bf(v.x); o.y = (short)f2bf(v.y);
  o.z = (short)f2bf(v.z); o.w = (short)f2bf(v.w);
  *(short4v*)(out + g * 262144 + off) = o;
}

// ---- kernel 2: fused windowed attention, one 1024-thread workgroup per (b, window) ----
// 16 waves, all co-resident (LDS caps at 1 block/CU) -> hard 128-reg/wave budget.
// Round-3 failure: compiler unroll/hoist of the kk loop exploded register
// pressure -> 290 MB/dispatch scratch traffic. Fix: rolled kk loop (#pragma
// unroll 1) + 1-deep b prefetch, and all fragment bounds-guards removed
// (junk rows/cols are discarded row-locally or masked by index in softmax;
// only VT tp-pads must be zeroed since 0*NaN=NaN inside MFMA).
__global__ __launch_bounds__(1024, 4) void wattn_kernel(
    const float* __restrict__ x, const short* __restrict__ wcvt,
    const float* __restrict__ qb, const float* __restrict__ kb, const float* __restrict__ vb,
    const float* __restrict__ btab, float* __restrict__ out) {
  __shared__ __align__(16) char sm[LDS_TOTAL];
  const int tid  = threadIdx.x;
  const int lane = tid & 63;
  const int wave = tid >> 6;       // 0..15
  const int bwi  = blockIdx.x;     // b*64 + wi
  const int bb   = bwi >> 6, wi = bwi & 63;
  const int l15  = lane & 15;
  const int l4   = lane >> 4;
  const int ig   = l4 * 4;

  // stage bias table (f32, 169*8)
  for (int i = tid; i < 169 * 8; i += 1024)
    *(float*)(sm + LDS_BIAS + i * 4) = btab[i];

  // stage x tile -> XT bf16 [49][512], row-XOR swizzle
  {
    const float* xb = x + (size_t)bb * (3136 * 512);
    const int whi = (wi >> 3) * 7, wlo = (wi & 7) * 7;
    for (int idx = tid; idx < 49 * 128; idx += 1024) {
      int t = idx >> 7, c4 = idx & 127;
      int yt = (t * 37) >> 8, xt = t - yt * 7;
      int l = (whi + yt) * 56 + wlo + xt;
      float4v v = *(const float4v*)(xb + l * 512 + c4 * 4);
      short4v o;
      o.x = (short)f2bf(v.x); o.y = (short)f2bf(v.y);
      o.z = (short)f2bf(v.z); o.w = (short)f2bf(v.w);
      int byte = t * 1024 + c4 * 8;
      *(short4v*)(sm + (byte ^ ((t & 7) << 4))) = o;
    }
  }
  __syncthreads();

  const int wcol = wave * 32;

  // ---- three projection GEMMs: P = XT @ W^T + b ----
  for (int g = 0; g < 3; ++g) {
    const short* wt = wcvt + g * 262144;
    const float* bias = (g == 0) ? qb : (g == 1) ? kb : vb;
    float4v acc[4][2];
#pragma unroll
    for (int m = 0; m < 4; ++m)
#pragma unroll
      for (int n = 0; n < 2; ++n) acc[m][n] = (float4v)0.f;

    // weight base pointers for this wave's two 16-col groups
    const short* wp0 = wt + (wcol + l15) * 512 + l4 * 8;
    const short* wp1 = wp0 + 16 * 512;
    bf16x8 b0 = __builtin_bit_cast(bf16x8, *(const short8*)(wp0));
    bf16x8 b1 = __builtin_bit_cast(bf16x8, *(const short8*)(wp1));

#pragma unroll 1
    for (int kk = 0; kk < 16; ++kk) {
      // prefetch next-kk weight fragments ((kk+1)&15 wraps: safe, discarded)
      const int nko = ((kk + 1) & 15) * 32;
      bf16x8 nb0 = __builtin_bit_cast(bf16x8, *(const short8*)(wp0 + nko));
      bf16x8 nb1 = __builtin_bit_cast(bf16x8, *(const short8*)(wp1 + nko));

      const int c = kk * 64 + l4 * 16;   // byte col within XT row
      bf16x8 a[4];
#pragma unroll
      for (int m = 0; m < 4; ++m) {
        int row = m * 16 + l15;          // rows >=49 read junk; discarded row-locally
        a[m] = __builtin_bit_cast(bf16x8, *(const short8*)(sm + row * 1024 + (c ^ ((row & 7) << 4))));
      }
#pragma unroll
      for (int m = 0; m < 4; ++m) {
        acc[m][0] = __builtin_amdgcn_mfma_f32_16x16x32_bf16(a[m], b0, acc[m][0], 0, 0, 0);
        acc[m][1] = __builtin_amdgcn_mfma_f32_16x16x32_bf16(a[m], b1, acc[m][1], 0, 0, 0);
      }
      b0 = nb0;
      b1 = nb1;
    }

    if (g < 2) {
      const int base = (g == 0) ? LDS_PQ : LDS_PK;
#pragma unroll
      for (int n = 0; n < 2; ++n) {
        int o = wcol + n * 16 + l15;
        float bv = bias[o];
#pragma unroll
        for (int m = 0; m < 4; ++m)
#pragma unroll
          for (int r = 0; r < 4; ++r) {
            int t = m * 16 + ig + r;
            if (t < 49) {
              int s = t * 8 + (o >> 6);
              int flat = s * 128 + (o & 63) * 2;
              *(unsigned short*)(sm + base + (flat ^ ((s & 7) << 4))) = f2bf(acc[m][n][r] + bv);
            }
          }
      }
    } else {
      __syncthreads();  // all waves done reading XT; region A becomes VT
#pragma unroll
      for (int n = 0; n < 2; ++n) {
        int o = wcol + n * 16 + l15;
        float bv = bias[o];
        int dd = o & 63;
#pragma unroll
        for (int m = 0; m < 4; ++m)
#pragma unroll
          for (int r = 0; r < 4; ++r) {
            int t = m * 16 + ig + r;
            if (t < 49) {
              int s = t * 8 + (o >> 6);
              int h2 = (s * 1339) >> 16;       // s / 49
              int tp = s - h2 * 49;
              *(unsigned short*)(sm + h2 * 7168 + dd * 112 + tp * 2) = f2bf(acc[m][n][r] + bv);
            }
          }
      }
      // zero VT pads t' = 49..55 (0*NaN=NaN inside MFMA -> pads must be real zeros)
      if (tid < 512) {
        int h2 = tid >> 6, dd = tid & 63;
        char* p = sm + h2 * 7168 + dd * 112;
#pragma unroll
        for (int q = 49; q < 56; ++q) *(unsigned short*)(p + q * 2) = 0;
      }
      __syncthreads();
    }
  }

  // ---- attention: wave pair (h, h+8) -> head h; 'half' owns row m-tiles {half*2, half*2+1} ----
  const int h    = wave & 7;
  const int half = wave >> 3;
  const float* bias_f = (const float*)(sm + LDS_BIAS);

  float4v sc[2][4];
#pragma unroll
  for (int mm = 0; mm < 2; ++mm)
#pragma unroll
    for (int n = 0; n < 4; ++n) sc[mm][n] = (float4v)0.f;

#pragma unroll
  for (int ks = 0; ks < 2; ++ks) {
    const int dd = ks * 32 + l4 * 8;
    bf16x8 a[2], b[4];
#pragma unroll
    for (int mm = 0; mm < 2; ++mm) {
      int s = h * 49 + (half * 2 + mm) * 16 + l15;   // rows >=49: junk, discarded
      int flat = s * 128 + dd * 2;
      a[mm] = __builtin_bit_cast(bf16x8, *(const short8*)(sm + LDS_PQ + (flat ^ ((s & 7) << 4))));
    }
#pragma unroll
    for (int n = 0; n < 4; ++n) {
      int s = h * 49 + n * 16 + l15;                 // cols >=49: junk, masked by index below
      int flat = s * 128 + dd * 2;
      b[n] = __builtin_bit_cast(bf16x8, *(const short8*)(sm + LDS_PK + (flat ^ ((s & 7) << 4))));
    }
#pragma unroll
    for (int mm = 0; mm < 2; ++mm)
#pragma unroll
      for (int n = 0; n < 4; ++n)
        sc[mm][n] = __builtin_amdgcn_mfma_f32_16x16x32_bf16(a[mm], b[n], sc[mm][n], 0, 0, 0);
  }

  // softmax on this wave's rows, in place (row i spread over 16 lanes x 4 n-tiles)
#pragma unroll
  for (int mm = 0; mm < 2; ++mm)
#pragma unroll
    for (int r = 0; r < 4; ++r) {
      int i = (half * 2 + mm) * 16 + ig + r;
      int yi = (i * 37) >> 8, xi = i - yi * 7;
      float mx = -1e30f;
#pragma unroll
      for (int n = 0; n < 4; ++n) {
        int j = n * 16 + l15;
        float v = -1e30f;
        if (i < 49 && j < 49) {
          int yj = (j * 37) >> 8, xj = j - yj * 7;
          int idx = (yi - yj + 6) * 13 + (xi - xj + 6);
          v = sc[mm][n][r] * 0.125f + bias_f[idx * 8 + h];
        }
        sc[mm][n][r] = v;
        mx = fmaxf(mx, v);
      }
      mx = fmaxf(mx, __shfl_xor(mx, 1));
      mx = fmaxf(mx, __shfl_xor(mx, 2));
      mx = fmaxf(mx, __shfl_xor(mx, 4));
      mx = fmaxf(mx, __shfl_xor(mx, 8));
      float ssum = 0.f;
#pragma unroll
      for (int n = 0; n < 4; ++n) {
        float e = (sc[mm][n][r] > -1e29f) ? __expf(sc[mm][n][r] - mx) : 0.f;
        sc[mm][n][r] = e;
        ssum += e;
      }
      ssum += __shfl_xor(ssum, 1);
      ssum += __shfl_xor(ssum, 2);
      ssum += __shfl_xor(ssum, 4);
      ssum += __shfl_xor(ssum, 8);
      float inv = 1.f / ssum;
#pragma unroll
      for (int n = 0; n < 4; ++n) sc[mm][n][r] *= inv;
    }

  __syncthreads();  // Pq/Pk dead for ALL waves -> overlay attn (per head, [64][64] bf16 swizzled)
  const int ovb = LDS_PQ + h * 8192;
#pragma unroll
  for (int mm = 0; mm < 2; ++mm)
#pragma unroll
    for (int r = 0; r < 4; ++r) {
      int i = (half * 2 + mm) * 16 + ig + r;
      if (i < 49) {
        int rowbase = i * 128;
        int swz = (i & 7) << 4;
#pragma unroll
        for (int n = 0; n < 4; ++n) {
          int j = n * 16 + l15;
          *(unsigned short*)(sm + ovb + ((rowbase + j * 2) ^ swz)) = f2bf(sc[mm][n][r]);
        }
      }
    }
  __syncthreads();

  // PV: out = attn @ V  (A rows = this wave's half; B from VT[h][dd][t'], full 64 cols)
  float4v oacc[2][4];
#pragma unroll
  for (int mm = 0; mm < 2; ++mm)
#pragma unroll
    for (int n = 0; n < 4; ++n) oacc[mm][n] = (float4v)0.f;

#pragma unroll
  for (int ks = 0; ks < 2; ++ks) {
    const int tp0 = ks * 32 + l4 * 8;
    bf16x8 a[2], b[4];
#pragma unroll
    for (int mm = 0; mm < 2; ++mm) {
      int i = (half * 2 + mm) * 16 + l15;            // rows >=49: junk, discarded
      int flat = i * 128 + tp0 * 2;
      a[mm] = __builtin_bit_cast(bf16x8, *(const short8*)(sm + ovb + (flat ^ ((i & 7) << 4))));
    }
    const int tt = (tp0 >= 56) ? 0 : tp0;  // clamp: attn cols >=49 are exact zeros
#pragma unroll
    for (int n = 0; n < 4; ++n) {
      int dd = n * 16 + l15;
      b[n] = __builtin_bit_cast(bf16x8, *(const short8*)(sm + h * 7168 + dd * 112 + tt * 2));
    }
#pragma unroll
    for (int mm = 0; mm < 2; ++mm)
#pragma unroll
      for (int n = 0; n < 4; ++n)
        oacc[mm][n] = __builtin_amdgcn_mfma_f32_16x16x32_bf16(a[mm], b[n], oacc[mm][n], 0, 0, 0);
  }

  // output: flat [b][wi][h][t'][dd]; full 256-B rows per wave
  float* op = out + (size_t)bwi * 25088 + h * 3136;
#pragma unroll
  for (int mm = 0; mm < 2; ++mm)
#pragma unroll
    for (int r = 0; r < 4; ++r) {
      int tp = (half * 2 + mm) * 16 + ig + r;
      if (tp < 49) {
#pragma unroll
        for (int n = 0; n < 4; ++n)
          op[tp * 64 + n * 16 + l15] = oacc[mm][n][r];
      }
    }
}

extern "C" void kernel_launch(void* const* d_in, const int* in_sizes, int n_in,
                              void* d_out, int out_size, void* d_ws, size_t ws_size,
                              hipStream_t stream) {
  const float* x    = (const float*)d_in[0];
  const float* q_w  = (const float*)d_in[1];
  const float* q_b  = (const float*)d_in[2];
  const float* k_w  = (const float*)d_in[3];
  const float* k_b  = (const float*)d_in[4];
  const float* v_w  = (const float*)d_in[5];
  const float* v_b  = (const float*)d_in[6];
  const float* btab = (const float*)d_in[7];
  short* wcvt = (short*)d_ws;  // 3 * 512 * 512 bf16 = 1.5 MB

  hipLaunchKernelGGL(wconv_kernel, dim3(768), dim3(256), 0, stream, q_w, k_w, v_w, wcvt);
  hipLaunchKernelGGL(wattn_kernel, dim3(1024), dim3(1024), 0, stream,
                     x, wcvt, q_b, k_b, v_b, btab, (float*)d_out);
}